// Round 6
// baseline (245.126 us; speedup 1.0000x reference)
//
#include <hip/hip_runtime.h>
#include <math.h>

#define BATCH  8
#define SEQLEN 4096
#define HID    1024
#define STATE  64
#define NC     16
#define TC     (SEQLEN / NC)   // 256 steps per chunk
#define TG     4               // time-group / prefetch depth

// ws layout (bytes):
//   pa_t: [0, 256K)  pw_t: [256K, 512K)  pE_t: [512K, 768K)   (all [n][d] transposed)
//   zl:   [1M, 1M + (NC-1)*BATCH*STATE*HID*4) = 30 MB, layout [c][b][n][d]
#define WS_PA 0
#define WS_PW (256 * 1024)
#define WS_PE (512 * 1024)
#define WS_ZL (1024 * 1024)

// ---------------------------------------------------------------- K0: params
// Reads A,Bm,C in native [d][n] layout (coalesced); writes transposed [n][d].
__global__ void k0_params(const float* __restrict__ A, const float* __restrict__ Bm,
                          const float* __restrict__ C, const float* __restrict__ dt,
                          float* __restrict__ pa, float* __restrict__ pw,
                          float* __restrict__ pE) {
    int i = blockIdx.x * 256 + threadIdx.x;
    if (i >= HID * STATE) return;
    int d = i >> 6, n = i & (STATE - 1);
    float aexp = expf(A[i]);
    float dtn  = dt[n];
    float a    = expf(-aexp * dtn);
    pa[n * HID + d] = a;
    pw[n * HID + d] = C[i] * (Bm[i] * (1.0f - a) / aexp);   // C * dB
    pE[n * HID + d] = expf(-aexp * dtn * (float)TC);        // a^TC
}

// ------------------------------------------- K1: chunk-local end states
// 1 lane = 1 channel; 64 states in registers. Wave = 64 consecutive channels.
__global__ __launch_bounds__(256, 2) void k1_locals(const float* __restrict__ u,
                                                    const float* __restrict__ pa,
                                                    float* __restrict__ zl) {
    int wid  = (blockIdx.x * 256 + threadIdx.x) >> 6;
    int lane = threadIdx.x & 63;
    int dset = wid & 15;
    int b    = (wid >> 4) & 7;
    int c    = wid >> 7;                 // chunk 0..NC-2
    int d    = dset * 64 + lane;

    float a[STATE], z[STATE];
    #pragma unroll
    for (int n = 0; n < STATE; n++) a[n] = pa[n * HID + d];   // coalesced per n
    #pragma unroll
    for (int n = 0; n < STATE; n++) z[n] = 0.f;

    const float* up = u + ((size_t)b * SEQLEN + (size_t)c * TC) * HID + d;

    float ubuf[TG];
    #pragma unroll
    for (int i = 0; i < TG; i++) ubuf[i] = up[(size_t)i * HID];

    for (int t0 = 0; t0 < TC; t0 += TG) {
        int nb = t0 + TG;
        if (nb > TC - TG) nb = TC - TG;                       // wave-uniform clamp
        const float* un = up + (size_t)nb * HID;
        float unext[TG];
        #pragma unroll
        for (int i = 0; i < TG; i++) unext[i] = un[(size_t)i * HID];

        #pragma unroll
        for (int i = 0; i < TG; i++) {
            float us = ubuf[i];
            #pragma unroll
            for (int n = 0; n < STATE; n++) z[n] = fmaf(a[n], z[n], us);
        }
        #pragma unroll
        for (int i = 0; i < TG; i++) ubuf[i] = unext[i];
    }

    float* zp = zl + ((size_t)(c * BATCH + b) * STATE) * HID + d;
    #pragma unroll
    for (int n = 0; n < STATE; n++) zp[(size_t)n * HID] = z[n];  // coalesced per n
}

// ---------------------------------- K2: prefix scan over chunks (in-place in zl)
__global__ void k2_scan(const float* __restrict__ pE, float* __restrict__ zl) {
    int i = blockIdx.x * 256 + threadIdx.x;           // over B*STATE*HID = 512K
    float E = pE[i & (STATE * HID - 1)];              // index = n*HID + d
    size_t stride = (size_t)BATCH * STATE * HID;
    float g = zl[i];                                   // slot0 already global
    for (int c = 1; c < NC - 1; c++) {
        float v = zl[i + c * stride];
        g = fmaf(E, g, v);
        zl[i + c * stride] = g;                        // slot c = global end of chunk c
    }
}

// --------------------------------------------------- K3: main pass with outputs
__global__ __launch_bounds__(256, 2) void k3_main(const float* __restrict__ u,
                                                  const float* __restrict__ Dv,
                                                  const float* __restrict__ pa,
                                                  const float* __restrict__ pw,
                                                  const float* __restrict__ zl,
                                                  float* __restrict__ out) {
    int wid  = (blockIdx.x * 256 + threadIdx.x) >> 6;
    int lane = threadIdx.x & 63;
    int dset = wid & 15;
    int b    = (wid >> 4) & 7;
    int c    = wid >> 7;                 // chunk 0..NC-1
    int d    = dset * 64 + lane;

    float a[STATE], w[STATE], z[STATE];
    #pragma unroll
    for (int n = 0; n < STATE; n++) a[n] = pa[n * HID + d];
    #pragma unroll
    for (int n = 0; n < STATE; n++) w[n] = pw[n * HID + d];
    if (c == 0) {
        #pragma unroll
        for (int n = 0; n < STATE; n++) z[n] = 0.f;
    } else {
        const float* zp = zl + ((size_t)((c - 1) * BATCH + b) * STATE) * HID + d;
        #pragma unroll
        for (int n = 0; n < STATE; n++) z[n] = zp[(size_t)n * HID];
    }

    float dvd = Dv[d];
    const float* up = u   + ((size_t)b * SEQLEN + (size_t)c * TC) * HID + d;
    float*       po = out + ((size_t)b * SEQLEN + (size_t)c * TC) * HID + d;

    float ubuf[TG];
    #pragma unroll
    for (int i = 0; i < TG; i++) ubuf[i] = up[(size_t)i * HID];

    for (int t0 = 0; t0 < TC; t0 += TG) {
        int nb = t0 + TG;
        if (nb > TC - TG) nb = TC - TG;                       // wave-uniform clamp
        const float* un = up + (size_t)nb * HID;
        float unext[TG];
        #pragma unroll
        for (int i = 0; i < TG; i++) unext[i] = un[(size_t)i * HID];

        #pragma unroll
        for (int i = 0; i < TG; i++) {
            float us = ubuf[i];
            #pragma unroll
            for (int n = 0; n < STATE; n++) z[n] = fmaf(a[n], z[n], us);
            // lane-local dot over 64 states: 4 independent chains
            float acc0 = z[0] * w[0];
            float acc1 = z[1] * w[1];
            float acc2 = z[2] * w[2];
            float acc3 = z[3] * w[3];
            #pragma unroll
            for (int n = 4; n < STATE; n += 4) {
                acc0 = fmaf(z[n + 0], w[n + 0], acc0);
                acc1 = fmaf(z[n + 1], w[n + 1], acc1);
                acc2 = fmaf(z[n + 2], w[n + 2], acc2);
                acc3 = fmaf(z[n + 3], w[n + 3], acc3);
            }
            float y = (acc0 + acc1) + (acc2 + acc3);
            po[(size_t)(t0 + i) * HID] = fmaf(dvd, us, y);    // coalesced 256B store
        }
        #pragma unroll
        for (int i = 0; i < TG; i++) ubuf[i] = unext[i];
    }
}

extern "C" void kernel_launch(void* const* d_in, const int* in_sizes, int n_in,
                              void* d_out, int out_size, void* d_ws, size_t ws_size,
                              hipStream_t stream) {
    const float* u  = (const float*)d_in[0];
    const float* A  = (const float*)d_in[1];
    const float* Bm = (const float*)d_in[2];
    const float* C  = (const float*)d_in[3];
    const float* Dv = (const float*)d_in[4];
    const float* dt = (const float*)d_in[5];
    float* out = (float*)d_out;

    char* ws = (char*)d_ws;
    float* pa = (float*)(ws + WS_PA);
    float* pw = (float*)(ws + WS_PW);
    float* pE = (float*)(ws + WS_PE);
    float* zl = (float*)(ws + WS_ZL);

    k0_params<<<(HID * STATE) / 256, 256, 0, stream>>>(A, Bm, C, dt, pa, pw, pE);
    // k1: 16 dsets * 8 batches * (NC-1) chunks waves, 4 waves/block
    k1_locals<<<(16 * 8 * (NC - 1)) / 4, 256, 0, stream>>>(u, pa, zl);
    k2_scan<<<(BATCH * STATE * HID) / 256, 256, 0, stream>>>(pE, zl);
    // k3: 16 dsets * 8 batches * NC chunks waves, 4 waves/block
    k3_main<<<(16 * 8 * NC) / 4, 256, 0, stream>>>(u, Dv, pa, pw, zl, out);
}

// Round 7
// 201.180 us; speedup vs baseline: 1.2184x; 1.2184x over previous
//
#include <hip/hip_runtime.h>
#include <math.h>

#define BATCH  8
#define SEQLEN 4096
#define HID    1024
#define STATE  64
#define NC     16
#define TC     (SEQLEN / NC)   // 256 steps per chunk
#define LPC    4               // lanes per channel
#define CW     16              // channels per wave (64 / LPC)
#define NS     16              // states per lane (STATE / LPC)
#define NP     8               // f32x2 pairs per lane
#define TG     8               // time-group / prefetch depth

typedef float f32x2 __attribute__((ext_vector_type(2)));

// ws layout (bytes):
//   pa: [0, 256K)  pw: [256K, 512K)  pE: [512K, 768K)
//   zl: [1M, 1M + (NC-1)*BATCH*HID*STATE*4)  = 30 MB of chunk states
#define WS_PA 0
#define WS_PW (256 * 1024)
#define WS_PE (512 * 1024)
#define WS_ZL (1024 * 1024)

// quad-lane sum via DPP (pure VALU; avoids DS shfl + lgkmcnt stall)
__device__ __forceinline__ float quad_reduce_add(float y) {
    int t = __builtin_amdgcn_mov_dpp(__builtin_bit_cast(int, y), 0xB1, 0xF, 0xF, true); // quad_perm [1,0,3,2]
    y += __builtin_bit_cast(float, t);
    t = __builtin_amdgcn_mov_dpp(__builtin_bit_cast(int, y), 0x4E, 0xF, 0xF, true);     // quad_perm [2,3,0,1]
    y += __builtin_bit_cast(float, t);
    return y;
}

// ---------------------------------------------------------------- K0: params
__global__ void k0_params(const float* __restrict__ A, const float* __restrict__ Bm,
                          const float* __restrict__ C, const float* __restrict__ dt,
                          float* __restrict__ pa, float* __restrict__ pw,
                          float* __restrict__ pE) {
    int i = blockIdx.x * 256 + threadIdx.x;
    if (i >= HID * STATE) return;
    int n = i & (STATE - 1);
    float aexp = expf(A[i]);
    float dtn  = dt[n];
    float a    = expf(-aexp * dtn);
    pa[i] = a;
    pw[i] = C[i] * (Bm[i] * (1.0f - a) / aexp);   // C * dB
    pE[i] = expf(-aexp * dtn * (float)TC);        // a^TC (chunk transition)
}

// ------------------------------------------- K1: chunk-local end states (z-space)
__global__ __launch_bounds__(256, 4) void k1_locals(const float* __restrict__ u,
                                                    const float* __restrict__ pa,
                                                    float* __restrict__ zl) {
    int wid  = (blockIdx.x * 256 + threadIdx.x) >> 6;   // wave task id
    int lane = threadIdx.x & 63;
    int dset = wid & 63;
    int b    = (wid >> 6) & 7;
    int c    = wid >> 9;                                // chunk 0..NC-2
    int dl   = lane >> 2, p = lane & 3;
    int d    = dset * CW + dl;

    f32x2 a2[NP], z2[NP];
    {
        const f32x2* pap = (const f32x2*)(pa + (size_t)d * STATE + p * NS);
        #pragma unroll
        for (int j = 0; j < NP; j++) a2[j] = pap[j];
    }
    #pragma unroll
    for (int j = 0; j < NP; j++) { z2[j].x = 0.f; z2[j].y = 0.f; }

    const float* up = u + ((size_t)b * SEQLEN + (size_t)c * TC) * HID + d;

    float ubuf[TG];
    #pragma unroll
    for (int i = 0; i < TG; i++) ubuf[i] = up[(size_t)i * HID];

    for (int t0 = 0; t0 < TC; t0 += TG) {
        int nb = t0 + TG;
        if (nb > TC - TG) nb = TC - TG;                 // wave-uniform clamp
        const float* un = up + (size_t)nb * HID;
        float unext[TG];
        #pragma unroll
        for (int i = 0; i < TG; i++) unext[i] = un[(size_t)i * HID];

        #pragma unroll
        for (int i = 0; i < TG; i++) {
            f32x2 us; us.x = ubuf[i]; us.y = ubuf[i];
            #pragma unroll
            for (int j = 0; j < NP; j++)
                z2[j] = __builtin_elementwise_fma(a2[j], z2[j], us);
        }
        #pragma unroll
        for (int i = 0; i < TG; i++) ubuf[i] = unext[i];
    }

    f32x2* zp = (f32x2*)(zl + (((size_t)c * BATCH + b) * HID + d) * STATE + p * NS);
    #pragma unroll
    for (int j = 0; j < NP; j++) zp[j] = z2[j];
}

// ---------------------------------- K2: prefix scan over chunks (in-place in zl)
__global__ void k2_scan(const float* __restrict__ pE, float* __restrict__ zl) {
    int i  = blockIdx.x * 256 + threadIdx.x;            // (b,d,n)
    int dn = i & (HID * STATE - 1);
    float E = pE[dn];
    size_t stride = (size_t)BATCH * HID * STATE;
    float g = zl[i];                                     // slot0 already global
    for (int c = 1; c < NC - 1; c++) {
        float v = zl[i + c * stride];
        g = fmaf(E, g, v);
        zl[i + c * stride] = g;                          // slot c = global end of chunk c
    }
}

// --------------------------------------------------- K3: main pass with outputs
__global__ __launch_bounds__(256, 4) void k3_main(const float* __restrict__ u,
                                                  const float* __restrict__ Dv,
                                                  const float* __restrict__ pa,
                                                  const float* __restrict__ pw,
                                                  const float* __restrict__ zl,
                                                  float* __restrict__ out) {
    int wid  = (blockIdx.x * 256 + threadIdx.x) >> 6;
    int lane = threadIdx.x & 63;
    int dset = wid & 63;
    int b    = (wid >> 6) & 7;
    int c    = wid >> 9;                                // chunk 0..NC-1
    int dl   = lane >> 2, p = lane & 3;
    int d    = dset * CW + dl;

    f32x2 a2[NP], w2[NP], z2[NP];
    {
        const f32x2* pap = (const f32x2*)(pa + (size_t)d * STATE + p * NS);
        const f32x2* pwp = (const f32x2*)(pw + (size_t)d * STATE + p * NS);
        #pragma unroll
        for (int j = 0; j < NP; j++) { a2[j] = pap[j]; w2[j] = pwp[j]; }
    }
    if (c == 0) {
        #pragma unroll
        for (int j = 0; j < NP; j++) { z2[j].x = 0.f; z2[j].y = 0.f; }
    } else {
        size_t stride = (size_t)BATCH * HID * STATE;
        const f32x2* zp = (const f32x2*)(zl + (size_t)(c - 1) * stride +
                                         ((size_t)b * HID + d) * STATE + p * NS);
        #pragma unroll
        for (int j = 0; j < NP; j++) z2[j] = zp[j];
    }

    float dvd = Dv[d];
    const float* up = u   + ((size_t)b * SEQLEN + (size_t)c * TC) * HID + d;
    float*       po = out + ((size_t)b * SEQLEN + (size_t)c * TC) * HID + d;

    float ubuf[TG];
    #pragma unroll
    for (int i = 0; i < TG; i++) ubuf[i] = up[(size_t)i * HID];

    for (int t0 = 0; t0 < TC; t0 += TG) {
        int nb = t0 + TG;
        if (nb > TC - TG) nb = TC - TG;                 // wave-uniform clamp
        const float* un = up + (size_t)nb * HID;
        float unext[TG];
        #pragma unroll
        for (int i = 0; i < TG; i++) unext[i] = un[(size_t)i * HID];

        // ---- compute phase: pure FMA issue, per-lane partial y for all TG steps
        float ylane[TG];
        #pragma unroll
        for (int i = 0; i < TG; i++) {
            f32x2 us; us.x = ubuf[i]; us.y = ubuf[i];
            #pragma unroll
            for (int j = 0; j < NP; j++)
                z2[j] = __builtin_elementwise_fma(a2[j], z2[j], us);
            f32x2 acc0 = z2[0] * w2[0];
            f32x2 acc1 = z2[1] * w2[1];
            #pragma unroll
            for (int j = 2; j < NP; j += 2) {
                acc0 = __builtin_elementwise_fma(z2[j + 0], w2[j + 0], acc0);
                acc1 = __builtin_elementwise_fma(z2[j + 1], w2[j + 1], acc1);
            }
            acc0 += acc1;
            ylane[i] = acc0.x + acc0.y;
        }
        // ---- reduce phase: TG independent DPP chains, pipelined
        #pragma unroll
        for (int i = 0; i < TG; i++) ylane[i] = quad_reduce_add(ylane[i]);
        // ---- store phase
        #pragma unroll
        for (int i = 0; i < TG; i++)
            po[(size_t)(t0 + i) * HID] = fmaf(dvd, ubuf[i], ylane[i]);

        #pragma unroll
        for (int i = 0; i < TG; i++) ubuf[i] = unext[i];
    }
}

extern "C" void kernel_launch(void* const* d_in, const int* in_sizes, int n_in,
                              void* d_out, int out_size, void* d_ws, size_t ws_size,
                              hipStream_t stream) {
    const float* u  = (const float*)d_in[0];
    const float* A  = (const float*)d_in[1];
    const float* Bm = (const float*)d_in[2];
    const float* C  = (const float*)d_in[3];
    const float* Dv = (const float*)d_in[4];
    const float* dt = (const float*)d_in[5];
    float* out = (float*)d_out;

    char* ws = (char*)d_ws;
    float* pa = (float*)(ws + WS_PA);
    float* pw = (float*)(ws + WS_PW);
    float* pE = (float*)(ws + WS_PE);
    float* zl = (float*)(ws + WS_ZL);

    k0_params<<<(HID * STATE) / 256, 256, 0, stream>>>(A, Bm, C, dt, pa, pw, pE);
    // k1: 64 dsets * 8 batches * (NC-1) chunks waves, 4 waves/block
    k1_locals<<<(64 * 8 * (NC - 1)) / 4, 256, 0, stream>>>(u, pa, zl);
    k2_scan<<<(BATCH * HID * STATE) / 256, 256, 0, stream>>>(pE, zl);
    // k3: 64 dsets * 8 batches * NC chunks waves, 4 waves/block
    k3_main<<<(64 * 8 * NC) / 4, 256, 0, stream>>>(u, Dv, pa, pw, zl, out);
}

// Round 8
// 174.252 us; speedup vs baseline: 1.4067x; 1.1545x over previous
//
#include <hip/hip_runtime.h>
#include <math.h>

#define BATCH  8
#define SEQLEN 4096
#define HID    1024
#define STATE  64
#define NC     16
#define TC     (SEQLEN / NC)   // 256 steps per chunk
#define TT     32              // time rows per LDS tile
#define NTILE  (TC / TT)       // 8 tiles per chunk
#define DBLK   64              // channels per block (4 waves x 16)
#define NS     16              // states per lane (4 lanes per channel)
#define NP     8               // f32x2 pairs per lane

typedef float f32x2 __attribute__((ext_vector_type(2)));

// ws layout (bytes):
//   pa: [0, 256K)  pw: [256K, 512K)  pE: [512K, 768K)
//   zl: [1M, 1M + (NC-1)*BATCH*HID*STATE*4)  = 30 MB of chunk states
#define WS_PA 0
#define WS_PW (256 * 1024)
#define WS_PE (512 * 1024)
#define WS_ZL (1024 * 1024)

// async global->LDS, 16B per lane. LDS dest is wave-uniform base + lane*16.
__device__ __forceinline__ void gload_lds16(const float* g, float* l) {
    __builtin_amdgcn_global_load_lds((const __attribute__((address_space(1))) void*)g,
                                     (__attribute__((address_space(3))) void*)l,
                                     16, 0, 0);
}

// quad-lane sum via DPP (pure VALU; 4 lanes per channel)
__device__ __forceinline__ float quad_reduce_add(float y) {
    int t = __builtin_amdgcn_mov_dpp(__builtin_bit_cast(int, y), 0xB1, 0xF, 0xF, true); // [1,0,3,2]
    y += __builtin_bit_cast(float, t);
    t = __builtin_amdgcn_mov_dpp(__builtin_bit_cast(int, y), 0x4E, 0xF, 0xF, true);     // [2,3,0,1]
    y += __builtin_bit_cast(float, t);
    return y;
}

// ---------------------------------------------------------------- K0: params
__global__ void k0_params(const float* __restrict__ A, const float* __restrict__ Bm,
                          const float* __restrict__ C, const float* __restrict__ dt,
                          float* __restrict__ pa, float* __restrict__ pw,
                          float* __restrict__ pE) {
    int i = blockIdx.x * 256 + threadIdx.x;
    if (i >= HID * STATE) return;
    int n = i & (STATE - 1);
    float aexp = expf(A[i]);
    float dtn  = dt[n];
    float a    = expf(-aexp * dtn);
    pa[i] = a;
    pw[i] = C[i] * (Bm[i] * (1.0f - a) / aexp);   // C * dB
    pE[i] = expf(-aexp * dtn * (float)TC);        // a^TC (chunk transition)
}

// ------------------------------------------- K1: chunk-local end states (z-space)
// block = (dset64, b, chunk); 4 waves x 16 channels; u staged in LDS tiles.
__global__ __launch_bounds__(256, 3) void k1_locals(const float* __restrict__ u,
                                                    const float* __restrict__ pa,
                                                    float* __restrict__ zl) {
    __shared__ float utile[2][TT * DBLK];
    int bid  = blockIdx.x;
    int dset = bid & 15;
    int b    = (bid >> 4) & 7;
    int c    = bid >> 7;                       // chunk 0..NC-2
    int w    = threadIdx.x >> 6;
    int lane = threadIdx.x & 63;
    int dl   = lane >> 2, p = lane & 3;
    int d    = dset * DBLK + w * 16 + dl;

    f32x2 a2[NP], z2[NP];
    {
        const f32x2* pap = (const f32x2*)(pa + (size_t)d * STATE + p * NS);
        #pragma unroll
        for (int j = 0; j < NP; j++) a2[j] = pap[j];
    }
    #pragma unroll
    for (int j = 0; j < NP; j++) { z2[j].x = 0.f; z2[j].y = 0.f; }

    const char* ubase = (const char*)(u + ((size_t)b * SEQLEN + (size_t)c * TC) * HID
                                        + (size_t)dset * DBLK);

    // issue tile `t` into buffer `buf`: 2 x 16B per lane, coalesced 256B rows
    #define ISSUE_TILE(t, buf)                                                        \
        {                                                                             \
            _Pragma("unroll")                                                         \
            for (int k = 0; k < 2; k++) {                                             \
                int off = w * 2048 + k * 1024 + lane * 16;   /* byte in 8KB tile */   \
                int row = off >> 8;                                                   \
                int col = off & 255;                                                  \
                const float* src = (const float*)(ubase + ((size_t)((t) * TT + row)) * (HID * 4) + col); \
                float* dst = &utile[buf][w * 512 + k * 256];                           \
                gload_lds16(src, dst);                                                \
            }                                                                         \
        }

    ISSUE_TILE(0, 0);
    __syncthreads();
    int cur = 0;
    for (int tile = 0; tile < NTILE; ++tile) {
        if (tile + 1 < NTILE) ISSUE_TILE(tile + 1, cur ^ 1);
        const float* ut = &utile[cur][w * 16 + dl];
        #pragma unroll
        for (int r = 0; r < TT; r++) {
            float uss = ut[r * DBLK];                 // ds_read_b32, 4-lane broadcast
            f32x2 us; us.x = uss; us.y = uss;
            #pragma unroll
            for (int j = 0; j < NP; j++)
                z2[j] = __builtin_elementwise_fma(a2[j], z2[j], us);
        }
        __syncthreads();                              // drains vmcnt too
        cur ^= 1;
    }

    f32x2* zp = (f32x2*)(zl + (((size_t)c * BATCH + b) * HID + d) * STATE + p * NS);
    #pragma unroll
    for (int j = 0; j < NP; j++) zp[j] = z2[j];
}

// ---------------------------------- K2: prefix scan over chunks (in-place in zl)
__global__ void k2_scan(const float* __restrict__ pE, float* __restrict__ zl) {
    int i  = blockIdx.x * 256 + threadIdx.x;            // (b,d,n)
    int dn = i & (HID * STATE - 1);
    float E = pE[dn];
    size_t stride = (size_t)BATCH * HID * STATE;
    float g = zl[i];                                     // slot0 already global
    for (int c = 1; c < NC - 1; c++) {
        float v = zl[i + c * stride];
        g = fmaf(E, g, v);
        zl[i + c * stride] = g;                          // slot c = global end of chunk c
    }
}

// --------------------------------------------------- K3: main pass with outputs
__global__ __launch_bounds__(256, 3) void k3_main(const float* __restrict__ u,
                                                  const float* __restrict__ Dv,
                                                  const float* __restrict__ pa,
                                                  const float* __restrict__ pw,
                                                  const float* __restrict__ zl,
                                                  float* __restrict__ out) {
    __shared__ float utile[2][TT * DBLK];
    int bid  = blockIdx.x;
    int dset = bid & 15;
    int b    = (bid >> 4) & 7;
    int c    = bid >> 7;                       // chunk 0..NC-1
    int w    = threadIdx.x >> 6;
    int lane = threadIdx.x & 63;
    int dl   = lane >> 2, p = lane & 3;
    int d    = dset * DBLK + w * 16 + dl;

    f32x2 a2[NP], w2[NP], z2[NP];
    {
        const f32x2* pap = (const f32x2*)(pa + (size_t)d * STATE + p * NS);
        const f32x2* pwp = (const f32x2*)(pw + (size_t)d * STATE + p * NS);
        #pragma unroll
        for (int j = 0; j < NP; j++) { a2[j] = pap[j]; w2[j] = pwp[j]; }
    }
    if (c == 0) {
        #pragma unroll
        for (int j = 0; j < NP; j++) { z2[j].x = 0.f; z2[j].y = 0.f; }
    } else {
        size_t stride = (size_t)BATCH * HID * STATE;
        const f32x2* zp = (const f32x2*)(zl + (size_t)(c - 1) * stride +
                                         ((size_t)b * HID + d) * STATE + p * NS);
        #pragma unroll
        for (int j = 0; j < NP; j++) z2[j] = zp[j];
    }

    float dvd = Dv[d];
    const char* ubase = (const char*)(u + ((size_t)b * SEQLEN + (size_t)c * TC) * HID
                                        + (size_t)dset * DBLK);
    float* po = out + ((size_t)b * SEQLEN + (size_t)c * TC) * HID + d;

    ISSUE_TILE(0, 0);
    __syncthreads();
    int cur = 0;
    for (int tile = 0; tile < NTILE; ++tile) {
        if (tile + 1 < NTILE) ISSUE_TILE(tile + 1, cur ^ 1);
        const float* ut = &utile[cur][w * 16 + dl];
        float* po_t = po + (size_t)tile * TT * HID;
        #pragma unroll
        for (int r = 0; r < TT; r++) {
            float uss = ut[r * DBLK];                 // ds_read_b32, 4-lane broadcast
            f32x2 us; us.x = uss; us.y = uss;
            #pragma unroll
            for (int j = 0; j < NP; j++)
                z2[j] = __builtin_elementwise_fma(a2[j], z2[j], us);
            f32x2 acc0 = z2[0] * w2[0];
            f32x2 acc1 = z2[1] * w2[1];
            #pragma unroll
            for (int j = 2; j < NP; j += 2) {
                acc0 = __builtin_elementwise_fma(z2[j + 0], w2[j + 0], acc0);
                acc1 = __builtin_elementwise_fma(z2[j + 1], w2[j + 1], acc1);
            }
            acc0 += acc1;
            float y = acc0.x + acc0.y;
            y = quad_reduce_add(y);                   // sum 4 lanes of this channel
            po_t[(size_t)r * HID] = fmaf(dvd, uss, y);
        }
        __syncthreads();
        cur ^= 1;
    }
}

extern "C" void kernel_launch(void* const* d_in, const int* in_sizes, int n_in,
                              void* d_out, int out_size, void* d_ws, size_t ws_size,
                              hipStream_t stream) {
    const float* u  = (const float*)d_in[0];
    const float* A  = (const float*)d_in[1];
    const float* Bm = (const float*)d_in[2];
    const float* C  = (const float*)d_in[3];
    const float* Dv = (const float*)d_in[4];
    const float* dt = (const float*)d_in[5];
    float* out = (float*)d_out;

    char* ws = (char*)d_ws;
    float* pa = (float*)(ws + WS_PA);
    float* pw = (float*)(ws + WS_PW);
    float* pE = (float*)(ws + WS_PE);
    float* zl = (float*)(ws + WS_ZL);

    k0_params<<<(HID * STATE) / 256, 256, 0, stream>>>(A, Bm, C, dt, pa, pw, pE);
    // k1: 16 dsets * 8 b * 15 chunks
    k1_locals<<<16 * 8 * (NC - 1), 256, 0, stream>>>(u, pa, zl);
    k2_scan<<<(BATCH * HID * STATE) / 256, 256, 0, stream>>>(pE, zl);
    // k3: 16 dsets * 8 b * 16 chunks
    k3_main<<<16 * 8 * NC, 256, 0, stream>>>(u, Dv, pa, pw, zl, out);
}